// Round 12
// baseline (255.520 us; speedup 1.0000x reference)
//
#include <hip/hip_runtime.h>
#include <math.h>

// B=64, M=128, J=512, T=513 (padded to TPAD=544), E=256, H=16, D=16; out (64, 65664) fp32.

#define TPAD 544  // 17 * 32; rows 513..543 are zero pads (exp(0)=1 -> subtract 31 from l)
#define NROWS 34816  // 64 * TPAD

typedef __attribute__((ext_vector_type(8))) short bf16x8;   // 8 bf16 = 4 VGPR
typedef __attribute__((ext_vector_type(8))) unsigned short u16x8;
typedef __attribute__((ext_vector_type(4))) float f32x4;    // MFMA acc
typedef __attribute__((ext_vector_type(4))) unsigned short u16x4;

static __device__ inline unsigned short f2bf(float x) {     // RNE fp32->bf16
  unsigned u = __float_as_uint(x);
  return (unsigned short)((u + 0x7fffu + ((u >> 16) & 1u)) >> 16);
}
static __device__ inline float bf2f(unsigned short h) {
  return __uint_as_float(((unsigned)h) << 16);
}

// global -> LDS direct DMA, 16B per lane; ldst wave-uniform (HW adds lane*16),
// gsrc is per-lane (contiguous runs: base + lane*16).
#define GLD16(gsrc, ldst) \
  __builtin_amdgcn_global_load_lds((const __attribute__((address_space(1))) void*)(gsrc), \
                                   (__attribute__((address_space(3))) void*)(ldst), 16, 0, 0)

// ---------------------------------------------------------------------------
// ALL-W split+transpose -> CHUNK-MAJOR planes Wh/Wl[chunk 0..31][1024 cols][8]:
// cols 0..255 = Wq, 256..511 = Wk, 512..767 = Wv, 768..1023 = Wc.
// One block per col (grid 1024).
// ---------------------------------------------------------------------------
__global__ void prep_wt(const float* __restrict__ Wq, const float* __restrict__ Wk,
                        const float* __restrict__ Wv, const float* __restrict__ Wc,
                        unsigned short* __restrict__ Wh, unsigned short* __restrict__ Wl)
{
  __shared__ unsigned short sh[256], sl[256];
  const int c = blockIdx.x, k = threadIdx.x;     // c 0..1023
  const float* Ws = (c < 256) ? Wq : (c < 512) ? Wk : (c < 768) ? Wv : Wc;
  const float x = Ws[k * 256 + (c & 255)];
  const unsigned short h = f2bf(x);
  sh[k] = h; sl[k] = f2bf(x - bf2f(h));
  __syncthreads();
  if (k < 32)
    *(u16x8*)(Wh + ((size_t)k * 1024 + c) * 8) = *(const u16x8*)&sh[k * 8];
  else if (k < 64)
    *(u16x8*)(Wl + ((size_t)(k - 32) * 1024 + c) * 8) = *(const u16x8*)&sl[(k - 32) * 8];
}

// ---------------------------------------------------------------------------
// jobs_padded split -> CHUNK-MAJOR planes: Jh/Jl[chunk 0..31][34816 rows][8 bf16].
// Row r = (b, t): t=0 skip, 1..512 jobs, >=513 zero pads. Writes are
// lane-contiguous 1KB runs. grid 544 x 256 (wave w owns chunks w*8..w*8+8).
// ---------------------------------------------------------------------------
__global__ __launch_bounds__(256) void prep_jobs(
    const float* __restrict__ jobs, const float* __restrict__ skip,
    unsigned short* __restrict__ Jh, unsigned short* __restrict__ Jl)
{
  const int w = threadIdx.x >> 6, lane = threadIdx.x & 63;
  const int r = blockIdx.x * 64 + lane;          // 0..34815
  const int bb = r / TPAD, tt = r - bb * TPAD;
  const bool padr = (tt >= 513);
  const float* src = (tt == 0) ? skip : (jobs + ((size_t)(bb * 512 + tt - 1) << 8));
  #pragma unroll
  for (int i = 0; i < 8; ++i) {
    const int cc = w * 8 + i;                    // chunk 0..31
    u16x8 h8 = {}, l8 = {};
    if (!padr) {
      const float4 a = *(const float4*)(src + cc * 8);
      const float4 b = *(const float4*)(src + cc * 8 + 4);
      const float v[8] = {a.x,a.y,a.z,a.w, b.x,b.y,b.z,b.w};
      #pragma unroll
      for (int j = 0; j < 8; ++j) {
        const unsigned short hh = f2bf(v[j]);
        h8[j] = hh;
        l8[j] = f2bf(v[j] - bf2f(hh));
      }
    }
    const size_t o = ((size_t)cc * NROWS + r) * 8;
    *(u16x8*)(Jh + o) = h8;
    *(u16x8*)(Jl + o) = l8;
  }
}

// ---------------------------------------------------------------------------
// machine split -> CHUNK-MAJOR planes Mh/Ml[chunk 0..31][8192 rows][8 bf16].
// grid 128 x 256 (wave w owns chunks w*8..w*8+8). Dense, no pad logic.
// ---------------------------------------------------------------------------
__global__ __launch_bounds__(256) void prep_mach(
    const float* __restrict__ A,
    unsigned short* __restrict__ Mh, unsigned short* __restrict__ Ml)
{
  const int w = threadIdx.x >> 6, lane = threadIdx.x & 63;
  const int r = blockIdx.x * 64 + lane;          // 0..8191
  const float* src = A + ((size_t)r << 8);
  #pragma unroll
  for (int i = 0; i < 8; ++i) {
    const int cc = w * 8 + i;
    const float4 a = *(const float4*)(src + cc * 8);
    const float4 b = *(const float4*)(src + cc * 8 + 4);
    const float v[8] = {a.x,a.y,a.z,a.w, b.x,b.y,b.z,b.w};
    u16x8 h8, l8;
    #pragma unroll
    for (int j = 0; j < 8; ++j) {
      const unsigned short hh = f2bf(v[j]);
      h8[j] = hh;
      l8[j] = f2bf(v[j] - bf2f(hh));
    }
    const size_t o = ((size_t)cc * 8192 + r) * 8;
    *(u16x8*)(Mh + o) = h8;
    *(u16x8*)(Ml + o) = l8;
  }
}

// ---------------------------------------------------------------------------
// KV projection v4: K as before; V computed TRANSPOSED via operand swap.
// Tile 64x64, grid 8 x 544 = 4352 blocks; LDS 32KB (2 x 16KB dbuf).
// K-blocks (bx<4):  C[t][c] = J(rows by*64) @ Wk|Wv(cols 256+bx*64)
// V-blocks (bx>=4): C[d][t] = Wv(rows 512+(bx-4)*64) @ J(cols by*64) -> the
//   output IS the V-transposed layout: stores become 16-lane-contiguous 32B
//   segments along t (was 64-line u16x4 scatter -> L2 transaction bound).
//   16 | 544 so no store segment spans a batch boundary; J pads are zero ->
//   V^T[d][pad] = 0 exactly.
// Uniform staging: 4 contiguous-1KB loads/wave; vmcnt(4) depth-2 pipeline.
// C = Ah*Bh + Ah*Bl + Al*Bh (same three cross terms either orientation).
// ---------------------------------------------------------------------------
__global__ __launch_bounds__(256) void gemm_kv_mfma(
    const unsigned short* __restrict__ Jh, const unsigned short* __restrict__ Jl,
    const unsigned short* __restrict__ Wh, const unsigned short* __restrict__ Wl,
    unsigned short* __restrict__ Kh, unsigned short* __restrict__ Kl,
    unsigned short* __restrict__ Vth, unsigned short* __restrict__ Vtl)
{
  __shared__ __align__(128) char smem[32768];  // 2 x {Ah 4K|Al 4K|Bh 4K|Bl 4K}
  const int tid = threadIdx.x;
  const int lin = blockIdx.x + (blockIdx.y << 3);        // 0..4351
  const int xcd = lin & 7, idx = lin >> 3;               // bijective (4352%8==0)
  const int bx = idx & 7;                                // 0..3 K-col | 4..7 V-d
  const int by = xcd * 68 + (idx >> 3);                  // J row-tile 0..543
  const int w = __builtin_amdgcn_readfirstlane(tid >> 6);
  const int lane = tid & 63;
  const int wr = (w >> 1) << 5, wc = (w & 1) << 5;
  const int fm = lane & 15, fq = lane >> 4;
  const bool vblk = (bx >= 4);

  // wave w stages: A-hi|A-lo|B-hi|B-lo. K-blocks: A=J, B=W. V-blocks: A=W, B=J.
  const unsigned short* sp;
  size_t rstride, base;
  if (!vblk) {
    sp = (w == 0) ? Jh : (w == 1) ? Jl : (w == 2) ? Wh : Wl;
    rstride = (w < 2) ? (size_t)NROWS : (size_t)1024;
    base    = (w < 2) ? (size_t)(by * 64) : (size_t)(256 + bx * 64);
  } else {
    sp = (w == 0) ? Wh : (w == 1) ? Wl : (w == 2) ? Jh : Jl;
    rstride = (w < 2) ? (size_t)1024 : (size_t)NROWS;
    base    = (w < 2) ? (size_t)(512 + (bx - 4) * 64) : (size_t)(by * 64);
  }
  const char* srcb = (const char*)sp + (base + lane) * 16;

  auto STAGE = [&](int ks, int bsel) {
    char* dst = smem + bsel * 16384 + w * 4096;
    #pragma unroll
    for (int j = 0; j < 4; ++j)
      GLD16(srcb + ((size_t)(ks * 4 + j)) * rstride * 16, dst + j * 1024);
  };

  f32x4 acc[2][2] = {};

  STAGE(0, 0);
  STAGE(1, 1);

  #pragma unroll
  for (int ks = 0; ks < 8; ++ks) {
    if (ks < 7) asm volatile("s_waitcnt vmcnt(4)" ::: "memory");
    else        asm volatile("s_waitcnt vmcnt(0)" ::: "memory");
    __builtin_amdgcn_s_barrier();
    __builtin_amdgcn_sched_barrier(0);

    char* cur = smem + (ks & 1) * 16384;
    bf16x8 afh[2], afl[2], bfh[2], bfl[2];
    #pragma unroll
    for (int i = 0; i < 2; ++i) {
      const int ro = fq * 1024 + (wr + i * 16 + fm) * 16;
      const int co = fq * 1024 + (wc + i * 16 + fm) * 16;
      afh[i] = *(const bf16x8*)(cur + ro);
      afl[i] = *(const bf16x8*)(cur + 4096 + ro);
      bfh[i] = *(const bf16x8*)(cur + 8192 + co);
      bfl[i] = *(const bf16x8*)(cur + 12288 + co);
    }
    #pragma unroll
    for (int mi = 0; mi < 2; ++mi)
      #pragma unroll
      for (int ni = 0; ni < 2; ++ni) {
        acc[mi][ni] = __builtin_amdgcn_mfma_f32_16x16x32_bf16(afh[mi], bfl[ni], acc[mi][ni], 0, 0, 0);
        acc[mi][ni] = __builtin_amdgcn_mfma_f32_16x16x32_bf16(afl[mi], bfh[ni], acc[mi][ni], 0, 0, 0);
        acc[mi][ni] = __builtin_amdgcn_mfma_f32_16x16x32_bf16(afh[mi], bfh[ni], acc[mi][ni], 0, 0, 0);
      }

    __builtin_amdgcn_s_barrier();
    if (ks + 2 < 8) STAGE(ks + 2, ks & 1);
  }

  // ---- epilogue: RNE hi/lo bf16 planes ----
  if (!vblk) {
    // K planes, row-major [34816][256]; C[row=J-row][col=K-col]
    const int cb = bx * 64 + wc;
    #pragma unroll
    for (int mi = 0; mi < 2; ++mi) {
      #pragma unroll
      for (int r = 0; r < 4; ++r) {
        const int row = by * 64 + wr + mi * 16 + fq * 4 + r;
        const size_t rb = (size_t)row << 8;
        #pragma unroll
        for (int ni = 0; ni < 2; ++ni) {
          const int cc = cb + ni * 16 + fm;
          const float x = acc[mi][ni][r];
          const unsigned short hh = f2bf(x);
          Kh[rb + cc] = hh;
          Kl[rb + cc] = f2bf(x - bf2f(hh));
        }
      }
    }
  } else {
    // V transposed planes [b][256 d][544 t]; C[row=d-local][col=t-local].
    // 16-lane fm segments are contiguous in t and never cross b (16 | 544).
    #pragma unroll
    for (int mi = 0; mi < 2; ++mi) {
      #pragma unroll
      for (int r = 0; r < 4; ++r) {
        const int cc = (bx - 4) * 64 + wr + mi * 16 + fq * 4 + r;  // V col (d)
        #pragma unroll
        for (int ni = 0; ni < 2; ++ni) {
          const int tg = by * 64 + wc + ni * 16 + fm;   // global J row
          const int bb = tg / TPAD;
          const int tt = tg - bb * TPAD;
          const size_t vb = ((size_t)(bb * 256 + cc)) * TPAD + tt;
          const float x = acc[mi][ni][r];
          const unsigned short hh = f2bf(x);
          Vth[vb] = hh;
          Vtl[vb] = f2bf(x - bf2f(hh));
        }
      }
    }
  }
}

// ---------------------------------------------------------------------------
// proj_mfma: C(8192 x 256) = A(8192 x 256) @ W[:, cbase..cbase+256) (+bias)*scale,
// all operands pre-split chunk-major planes; output split planes [chunk][8192][8].
// Tile 64m x 64c, grid 4 x 128 = 512 blocks; LDS 32KB (2 x 16KB dbuf).
// 4 waves = 2x2 (32 rows x 32 cols), acc[2][2]; 4 contiguous-1KB loads/wave.
// Used for Q = machine@Wq (scale=0.25) and MH = OC@Wc + bc.
// ---------------------------------------------------------------------------
__global__ __launch_bounds__(256) void proj_mfma(
    const unsigned short* __restrict__ Ah_, const unsigned short* __restrict__ Al_,
    const unsigned short* __restrict__ Wh_, const unsigned short* __restrict__ Wl_,
    const int cbase, const float scale, const float* __restrict__ bias,
    unsigned short* __restrict__ Ch, unsigned short* __restrict__ Cl)
{
  __shared__ __align__(128) char smem[32768];  // 2 x {Ah 4K|Al 4K|Bh 4K|Bl 4K}
  const int tid = threadIdx.x;
  const int lin = blockIdx.x + (blockIdx.y << 2);        // 0..511
  const int virt = (lin & 7) * 64 + (lin >> 3);          // bijective (512%8==0)
  const int bx = virt & 3, by = virt >> 2;               // col-tile(64), row-tile(64)
  const int w = __builtin_amdgcn_readfirstlane(tid >> 6);
  const int lane = tid & 63;
  const int wr = (w >> 1) << 5, wc = (w & 1) << 5;
  const int fm = lane & 15, fq = lane >> 4;

  const unsigned short* sp = (w == 0) ? Ah_ : (w == 1) ? Al_ : (w == 2) ? Wh_ : Wl_;
  const size_t rstride = (w < 2) ? (size_t)8192 : (size_t)1024;
  const size_t base = (w < 2) ? (size_t)(by * 64) : (size_t)(cbase + bx * 64);
  const char* srcb = (const char*)sp + (base + lane) * 16;

  auto STAGE = [&](int ks, int bsel) {
    char* dst = smem + bsel * 16384 + w * 4096;
    #pragma unroll
    for (int j = 0; j < 4; ++j)
      GLD16(srcb + ((size_t)(ks * 4 + j)) * rstride * 16, dst + j * 1024);
  };

  f32x4 acc[2][2] = {};

  STAGE(0, 0);
  STAGE(1, 1);

  #pragma unroll
  for (int ks = 0; ks < 8; ++ks) {
    if (ks < 7) asm volatile("s_waitcnt vmcnt(4)" ::: "memory");
    else        asm volatile("s_waitcnt vmcnt(0)" ::: "memory");
    __builtin_amdgcn_s_barrier();
    __builtin_amdgcn_sched_barrier(0);

    char* cur = smem + (ks & 1) * 16384;
    bf16x8 afh[2], afl[2], bfh[2], bfl[2];
    #pragma unroll
    for (int i = 0; i < 2; ++i) {
      const int ro = fq * 1024 + (wr + i * 16 + fm) * 16;
      const int co = fq * 1024 + (wc + i * 16 + fm) * 16;
      afh[i] = *(const bf16x8*)(cur + ro);
      afl[i] = *(const bf16x8*)(cur + 4096 + ro);
      bfh[i] = *(const bf16x8*)(cur + 8192 + co);
      bfl[i] = *(const bf16x8*)(cur + 12288 + co);
    }
    #pragma unroll
    for (int mi = 0; mi < 2; ++mi)
      #pragma unroll
      for (int ni = 0; ni < 2; ++ni) {
        acc[mi][ni] = __builtin_amdgcn_mfma_f32_16x16x32_bf16(afh[mi], bfl[ni], acc[mi][ni], 0, 0, 0);
        acc[mi][ni] = __builtin_amdgcn_mfma_f32_16x16x32_bf16(afl[mi], bfh[ni], acc[mi][ni], 0, 0, 0);
        acc[mi][ni] = __builtin_amdgcn_mfma_f32_16x16x32_bf16(afh[mi], bfh[ni], acc[mi][ni], 0, 0, 0);
      }

    __builtin_amdgcn_s_barrier();
    if (ks + 2 < 8) STAGE(ks + 2, ks & 1);
  }

  // epilogue: x = acc*scale (+bias); split RNE hi/lo into chunk-major planes
  const int colb = bx * 64 + wc;
  #pragma unroll
  for (int mi = 0; mi < 2; ++mi) {
    #pragma unroll
    for (int r = 0; r < 4; ++r) {
      const int row = by * 64 + (w >> 1) * 32 + mi * 16 + fq * 4 + r;
      #pragma unroll
      for (int ni = 0; ni < 2; ++ni) {
        const int oc = colb + ni * 16 + fm;
        float x = acc[mi][ni][r] * scale;
        if (bias) x += bias[oc];
        const unsigned short hh = f2bf(x);
        const size_t o = ((size_t)(oc >> 3) * 8192 + row) * 8 + (oc & 7);
        Ch[o] = hh;
        Cl[o] = f2bf(x - bf2f(hh));
      }
    }
  }
}

// ---------------------------------------------------------------------------
// MFMA attention v9: one block per (h, b), 4 waves (m-half x t-half).
// Q read as pre-split planes (scale folded); K/V as pre-split planes (hi for
// lane groups 0,1; lo for 2,3); V transposed (contiguous t). Output written
// as split OC planes [chunk][8192][8] feeding proj_mfma directly.
// Pads t=513..543 are zero -> exp=1 exactly: subtract 31 from l.
// ---------------------------------------------------------------------------
__global__ __launch_bounds__(256, 4) void attn_mfma(
    const unsigned short* __restrict__ Qh, const unsigned short* __restrict__ Ql,
    const unsigned short* __restrict__ Kh, const unsigned short* __restrict__ Kl,
    const unsigned short* __restrict__ Vth, const unsigned short* __restrict__ Vtl,
    unsigned short* __restrict__ Och, unsigned short* __restrict__ Ocl)
{
  const int h = blockIdx.x, b = blockIdx.y;
  const int tid = threadIdx.x;
  const int lane = tid & 63;
  const int w = __builtin_amdgcn_readfirstlane(tid >> 6);
  const int g = lane >> 4, fm = lane & 15;
  const int mh = (w & 2) << 5;              // 0 or 64
  const int th = w & 1;                     // t-half
  const int send = th ? 17 : 9;             // steps [0,9) | [9,17)
  int s = th ? 9 : 0;

  __shared__ float red[2 * 64 * 21];        // 10.5 KB, stride-21 (conflict-free)

  const int col = h * 16;

  // ---- Q B-frags from pre-split planes: Bq1 = hi, Bq2 = lo (g<2) | 0 ----
  bf16x8 Bq1[4], Bq2[4];
  const bf16x8 zf = {};
  #pragma unroll
  for (int mt = 0; mt < 4; ++mt) {
    const size_t qo = ((size_t)(h * 2 + (g & 1)) * 8192
                      + (b * 128 + mh + mt * 16 + fm)) * 8;
    Bq1[mt] = *(const bf16x8*)(Qh + qo);
    Bq2[mt] = (g < 2) ? *(const bf16x8*)(Ql + qo) : zf;
  }

  f32x4 oT[4] = {};
  float lsum[4] = {0.f, 0.f, 0.f, 0.f};

  const int rA = ((fm & 12) << 1) + (fm & 3);   // permuted K row within step
  const int dbase = (g & 1) << 3;
  const unsigned short* kpl = ((g < 2) ? Kh : Kl)
      + ((((size_t)b * TPAD) + rA) << 8) + col + dbase;
  const unsigned short* vhp = Vth + ((size_t)(b * 256 + col + fm)) * TPAD + (g << 3);
  const unsigned short* vlp = Vtl + ((size_t)(b * 256 + col + fm)) * TPAD + (g << 3);

  for (; s < send; ++s) {
    const int t0 = s << 5;
    const bf16x8 KA = *(const bf16x8*)(kpl + ((size_t)t0 << 8));
    const bf16x8 KB = *(const bf16x8*)(kpl + ((size_t)(t0 + 4) << 8));
    const bf16x8 Vh = *(const bf16x8*)(vhp + t0);
    const bf16x8 Vl = *(const bf16x8*)(vlp + t0);

    #pragma unroll
    for (int mt = 0; mt < 4; ++mt) {
      f32x4 sA = {}, sB = {};
      sA = __builtin_amdgcn_mfma_f32_16x16x32_bf16(KA, Bq1[mt], sA, 0, 0, 0);
      sA = __builtin_amdgcn_mfma_f32_16x16x32_bf16(KA, Bq2[mt], sA, 0, 0, 0);
      sB = __builtin_amdgcn_mfma_f32_16x16x32_bf16(KB, Bq1[mt], sB, 0, 0, 0);
      sB = __builtin_amdgcn_mfma_f32_16x16x32_bf16(KB, Bq2[mt], sB, 0, 0, 0);
      float p[8];
      p[0] = __expf(sA[0]); p[1] = __expf(sA[1]); p[2] = __expf(sA[2]); p[3] = __expf(sA[3]);
      p[4] = __expf(sB[0]); p[5] = __expf(sB[1]); p[6] = __expf(sB[2]); p[7] = __expf(sB[3]);
      lsum[mt] += ((p[0] + p[1]) + (p[2] + p[3])) + ((p[4] + p[5]) + (p[6] + p[7]));
      bf16x8 Ph, Pl;
      #pragma unroll
      for (int jp = 0; jp < 4; ++jp) {
        const unsigned u0 = __float_as_uint(p[2*jp]);
        const unsigned u1 = __float_as_uint(p[2*jp+1]);
        ((unsigned*)&Ph)[jp] = __builtin_amdgcn_perm(u1, u0, 0x07060302u);
        const float r0 = p[2*jp]   - __uint_as_float(u0 & 0xffff0000u);
        const float r1 = p[2*jp+1] - __uint_as_float(u1 & 0xffff0000u);
        unsigned t0_ = __float_as_uint(r0); t0_ += 0x7fffu + ((t0_ >> 16) & 1u);
        unsigned t1_ = __float_as_uint(r1); t1_ += 0x7fffu + ((t1_ >> 16) & 1u);
        ((unsigned*)&Pl)[jp] = __builtin_amdgcn_perm(t1_, t0_, 0x07060302u);
      }
      oT[mt] = __builtin_amdgcn_mfma_f32_16x16x32_bf16(Vh, Ph, oT[mt], 0, 0, 0);
      oT[mt] = __builtin_amdgcn_mfma_f32_16x16x32_bf16(Vh, Pl, oT[mt], 0, 0, 0);
      oT[mt] = __builtin_amdgcn_mfma_f32_16x16x32_bf16(Vl, Ph, oT[mt], 0, 0, 0);
    }
  }

  // ---- pair reduce (t-half 1 -> t-half 0), then normalize + write planes ----
  float* slot = red + ((w >> 1) * 1344);
  const int base = lane * 21;
  if (th) {
    #pragma unroll
    for (int mt = 0; mt < 4; ++mt) {
      slot[base + 4 * mt + 0] = oT[mt][0];
      slot[base + 4 * mt + 1] = oT[mt][1];
      slot[base + 4 * mt + 2] = oT[mt][2];
      slot[base + 4 * mt + 3] = oT[mt][3];
      slot[base + 16 + mt]    = lsum[mt];
    }
  }
  __syncthreads();
  if (!th) {
    #pragma unroll
    for (int mt = 0; mt < 4; ++mt) {
      oT[mt][0] += slot[base + 4 * mt + 0];
      oT[mt][1] += slot[base + 4 * mt + 1];
      oT[mt][2] += slot[base + 4 * mt + 2];
      oT[mt][3] += slot[base + 4 * mt + 3];
      float v = lsum[mt] + slot[base + 16 + mt];
      v += __shfl_xor(v, 16);
      v += __shfl_xor(v, 32);
      const float inv = 1.f / (v - 31.f);     // remove 31 pad rows (exp(0)=1)
      // oT reg r = out[m][d = 4g + r] -> chunk h*2+(g>>1), slot (g&1)*4 + r
      const int row = b * 128 + mh + mt * 16 + fm;
      const size_t oo = ((size_t)(h * 2 + (g >> 1)) * 8192 + row) * 8 + ((g & 1) << 2);
      u16x4 oh, ol;
      #pragma unroll
      for (int r = 0; r < 4; ++r) {
        const float x = oT[mt][r] * inv;
        const unsigned short hh = f2bf(x);
        oh[r] = hh;
        ol[r] = f2bf(x - bf2f(hh));
      }
      *(u16x4*)(Och + oo) = oh;
      *(u16x4*)(Ocl + oo) = ol;
    }
  }
}

// ---------------------------------------------------------------------------
// Logits v3: tile 128m x 64t, grid 9 x 64 = 576 blocks; 48KB dbuf ->
// 3 blocks/CU. Waves 0/1 stage Mh/Ml (8 loads), 2/3 Jh/Jl (4 loads); counted
// vmcnt. Cheap tanh: e = exp(mask - 20/(exp(acc/8)+1)). tx=8 tail guarded +
// J-row clamped. Deterministic partials[b*9+tx]; sm_inv folded into sm_norm.
// ---------------------------------------------------------------------------
__global__ __launch_bounds__(256) void logits_mfma(
    const unsigned short* __restrict__ Mh, const unsigned short* __restrict__ Ml,
    const unsigned short* __restrict__ Jh, const unsigned short* __restrict__ Jl,
    const float* __restrict__ mask,
    float* __restrict__ out, float* __restrict__ partials)
{
  __shared__ __align__(128) char smem[49152];  // 2 x {Ah 8K|Al 8K|Bh 4K|Bl 4K}
  __shared__ float red[4];
  const int tid = threadIdx.x;
  const int lin = blockIdx.x + blockIdx.y * 9;           // 0..575
  const int virt = (lin & 7) * 72 + (lin >> 3);          // bijective (576%8==0)
  const int tx = virt % 9;                               // t-tile 0..8
  const int b  = virt / 9;
  const int w = __builtin_amdgcn_readfirstlane(tid >> 6);
  const int lane = tid & 63;
  const int wr = (w >> 1) << 6;              // m-half: 0 | 64
  const int wtc = (w & 1) << 5;              // t-half: 0 | 32
  const int fm = lane & 15, fq = lane >> 4;

  const unsigned short* sp = (w == 0) ? Mh : (w == 1) ? Ml : (w == 2) ? Jh : Jl;
  int jrow = b * TPAD + tx * 64 + lane;      // clamp tx=8 tail (guarded cols only)
  if (jrow > NROWS - 1) jrow = NROWS - 1;
  const char* srcb = (w < 2)
      ? (const char*)sp + ((size_t)(b * 128) + lane) * 16
      : (const char*)sp + (size_t)jrow * 16;

  auto STAGE = [&](int ks, int bsel) {
    char* buf = smem + bsel * 24576;
    if (w < 2) {                             // M planes: 128 rows, 8 loads
      char* dst = buf + (w ? 8192 : 0);
      #pragma unroll
      for (int j = 0; j < 8; ++j) {
        const int fq_ = j >> 1, half = j & 1;
        GLD16(srcb + (((size_t)(ks * 4 + fq_)) * 8192 + half * 64) * 16,
              dst + fq_ * 2048 + half * 1024);
      }
    } else {                                 // J planes: 64 rows, 4 loads
      char* dst = buf + 16384 + ((w == 3) ? 4096 : 0);
      #pragma unroll
      for (int j = 0; j < 4; ++j)
        GLD16(srcb + ((size_t)(ks * 4 + j)) * ((size_t)NROWS * 16),
              dst + j * 1024);
    }
  };

  f32x4 acc[4][2] = {};

  STAGE(0, 0);
  STAGE(1, 1);

  #pragma unroll
  for (int ks = 0; ks < 8; ++ks) {
    if (ks < 7) {
      if (w < 2) asm volatile("s_waitcnt vmcnt(8)" ::: "memory");
      else       asm volatile("s_waitcnt vmcnt(4)" ::: "memory");
    } else {
      asm volatile("s_waitcnt vmcnt(0)" ::: "memory");
    }
    __builtin_amdgcn_s_barrier();
    __builtin_amdgcn_sched_barrier(0);

    char* cur = smem + (ks & 1) * 24576;
    bf16x8 afh[4], afl[4], bfh[2], bfl[2];
    #pragma unroll
    for (int i = 0; i < 4; ++i) {
      const int ro = fq * 2048 + (wr + i * 16 + fm) * 16;
      afh[i] = *(const bf16x8*)(cur + ro);
      afl[i] = *(const bf16x8*)(cur + 8192 + ro);
    }
    #pragma unroll
    for (int n = 0; n < 2; ++n) {
      const int co = fq * 1024 + (wtc + n * 16 + fm) * 16;
      bfh[n] = *(const bf16x8*)(cur + 16384 + co);
      bfl[n] = *(const bf16x8*)(cur + 20480 + co);
    }
    #pragma unroll
    for (int mi = 0; mi < 4; ++mi)
      #pragma unroll
      for (int ni = 0; ni < 2; ++ni) {
        acc[mi][ni] = __builtin_amdgcn_mfma_f32_16x16x32_bf16(afh[mi], bfl[ni], acc[mi][ni], 0, 0, 0);
        acc[mi][ni] = __builtin_amdgcn_mfma_f32_16x16x32_bf16(afl[mi], bfh[ni], acc[mi][ni], 0, 0, 0);
        acc[mi][ni] = __builtin_amdgcn_mfma_f32_16x16x32_bf16(afh[mi], bfh[ni], acc[mi][ni], 0, 0, 0);
      }

    __builtin_amdgcn_s_barrier();
    if (ks + 2 < 8) STAGE(ks + 2, ks & 1);
  }

  // epilogue: e = exp(mask - 20/(exp(acc/8)+1)); write; deterministic partial
  float lsum = 0.f;
  #pragma unroll
  for (int mi = 0; mi < 4; ++mi) {
    #pragma unroll
    for (int r = 0; r < 4; ++r) {
      const int m = wr + mi * 16 + fq * 4 + r;
      #pragma unroll
      for (int ni = 0; ni < 2; ++ni) {
        const int t = tx * 64 + wtc + ni * 16 + fm;
        if (t < 513) {
          const float e2 = __expf(acc[mi][ni][r] * 0.125f);
          const float e  = __expf(mask[((size_t)(b * 128 + m)) * 513 + t]
                                  - 20.f / (e2 + 1.f));
          out[(size_t)b * 65664 + (size_t)m * 513 + t] = e;
          lsum += e;
        }
      }
    }
  }
  #pragma unroll
  for (int off = 32; off; off >>= 1) lsum += __shfl_xor(lsum, off);
  if (lane == 0) red[w] = lsum;
  __syncthreads();
  if (tid == 0)
    partials[b * 9 + tx] = (red[0] + red[1]) + (red[2] + red[3]);
}

// Normalize: inv computed inline from 9 deterministic partials (L1-hot).
__global__ __launch_bounds__(256) void sm_norm(float* __restrict__ out,
                                               const float* __restrict__ partials)
{
  const int i4 = blockIdx.x * 256 + threadIdx.x;
  if (i4 < 1050624) {
    const int b = i4 / 16416;
    float s = 0.f;
    #pragma unroll
    for (int i = 0; i < 9; ++i) s += partials[b * 9 + i];
    const float inv = 1.f / s;
    float4 v = ((float4*)out)[i4];
    v.x *= inv; v.y *= inv; v.z *= inv; v.w *= inv;
    ((float4*)out)[i4] = v;
  }
}

// ---------------------------------------------------------------------------
extern "C" void kernel_launch(void* const* d_in, const int* in_sizes, int n_in,
                              void* d_out, int out_size, void* d_ws, size_t ws_size,
                              hipStream_t stream)
{
  const float* machine = (const float*)d_in[0];
  const float* jobs    = (const float*)d_in[1];
  const float* mask    = (const float*)d_in[2];
  const float* Wq      = (const float*)d_in[3];
  const float* Wk      = (const float*)d_in[4];
  const float* Wv      = (const float*)d_in[5];
  const float* Wc      = (const float*)d_in[6];
  const float* bc      = (const float*)d_in[7];
  const float* skip    = (const float*)d_in[8];

  // Workspace (floats). Peak ~29,098,560 f ~ 116.4 MB.
  //   [0,        8912896)  Jh|Jl chunk-major jobs planes (LIVE until logits)
  //   [8912896, 17825792)  Kh|Kl planes [34816][256] (dead after attn)
  //        overlays after attn: Mh|Ml MH planes (proj2 output, 2.1M f)
  //   [17825792,26738688)  Vth|Vtl transposed planes [64][256][544]
  //   [26738688,27000832)  Wah|Wal all-W planes [32][1024][8] hi/lo
  //   [27000832,29097984)  Mch|Mcl machine planes [32][8192][8] hi/lo
  //   [29097984,29098560)  partials (576 f)
  // d_out (4,202,496 f) scratch pre-logits: Qh|Ql [0,2.1M f), Och|Ocl [2.1M,4.2M f).
  float* ws       = (float*)d_ws;
  unsigned short* JhP = (unsigned short*)ws;
  unsigned short* JlP = JhP + 8912896;
  unsigned short* KhP = (unsigned short*)(ws + 8912896);
  unsigned short* KlP = KhP + 8912896;
  unsigned short* VthP = (unsigned short*)(ws + 17825792);
  unsigned short* VtlP = VthP + 8912896;
  unsigned short* WahP = (unsigned short*)(ws + 26738688);
  unsigned short* WalP = WahP + 262144;
  unsigned short* MchP = (unsigned short*)(ws + 27000832);
  unsigned short* MclP = MchP + 2097152;
  unsigned short* MhP  = (unsigned short*)(ws + 8912896);   // overlays Kh (dead after attn)
  unsigned short* MlP  = MhP + 2097152;
  float* partials = ws + 29097984;
  float* out      = (float*)d_out;
  unsigned short* QhP  = (unsigned short*)out;              // d_out scratch
  unsigned short* QlP  = QhP + 2097152;
  unsigned short* OchP = QlP + 2097152;
  unsigned short* OclP = OchP + 2097152;

  // prep: all-W planes, jobs planes, machine planes (chunk-major pre-split)
  prep_wt<<<1024, 256, 0, stream>>>(Wq, Wk, Wv, Wc, WahP, WalP);
  prep_jobs<<<544, 256, 0, stream>>>(jobs, skip, JhP, JlP);
  prep_mach<<<128, 256, 0, stream>>>(machine, MchP, MclP);
  // K|V projection v4: V computed transposed via operand swap (coalesced stores)
  gemm_kv_mfma<<<dim3(8, 544), 256, 0, stream>>>(
      JhP, JlP, WahP, WalP, KhP, KlP, VthP, VtlP);
  // Q = machine @ Wq * 0.25 -> split planes (d_out scratch)
  proj_mfma<<<dim3(4, 128), 256, 0, stream>>>(
      MchP, MclP, WahP, WalP, 0, 0.25f, nullptr, QhP, QlP);
  // MFMA attention -> OC split planes (d_out scratch)
  attn_mfma<<<dim3(16, 64), 256, 0, stream>>>(
      QhP, QlP, KhP, KlP, VthP, VtlP, OchP, OclP);
  // MH = OC @ Wc + bc -> split planes (overlay K region)
  proj_mfma<<<dim3(4, 128), 256, 0, stream>>>(
      OchP, OclP, WahP, WalP, 768, 1.0f, bc, MhP, MlP);
  // logits v3 + fused exp epilogue + partials
  logits_mfma<<<dim3(9, 64), 256, 0, stream>>>(
      MhP, MlP, JhP, JlP, mask, out, partials);
  sm_norm<<<4104, 256, 0, stream>>>(out, partials);
}

// Round 14
// 240.643 us; speedup vs baseline: 1.0618x; 1.0618x over previous
//
#include <hip/hip_runtime.h>
#include <math.h>

// B=64, M=128, J=512, T=513 (padded to TPAD=544), E=256, H=16, D=16; out (64, 65664) fp32.

#define TPAD 544  // 17 * 32; rows 513..543 are zero pads (exp(0)=1 -> subtract 31 from l)
#define NROWS 34816  // 64 * TPAD

typedef __attribute__((ext_vector_type(8))) short bf16x8;   // 8 bf16 = 4 VGPR
typedef __attribute__((ext_vector_type(8))) unsigned short u16x8;
typedef __attribute__((ext_vector_type(4))) float f32x4;    // MFMA acc
typedef __attribute__((ext_vector_type(4))) unsigned short u16x4;

static __device__ inline unsigned short f2bf(float x) {     // RNE fp32->bf16
  unsigned u = __float_as_uint(x);
  return (unsigned short)((u + 0x7fffu + ((u >> 16) & 1u)) >> 16);
}
static __device__ inline float bf2f(unsigned short h) {
  return __uint_as_float(((unsigned)h) << 16);
}

// global -> LDS direct DMA, 16B per lane; ldst wave-uniform (HW adds lane*16),
// gsrc is per-lane (contiguous runs: base + lane*16).
#define GLD16(gsrc, ldst) \
  __builtin_amdgcn_global_load_lds((const __attribute__((address_space(1))) void*)(gsrc), \
                                   (__attribute__((address_space(3))) void*)(ldst), 16, 0, 0)

// ---------------------------------------------------------------------------
// prep_all: ONE launch for all input marshalling (3 independent passes co-run).
//   bid <  1024: W split+transpose -> Wh/Wl[chunk][1024 cols][8]
//                (cols 0..255 Wq | 256..511 Wk | 512..767 Wv | 768..1023 Wc)
//   bid < 1568:  jobs_padded split -> Jh/Jl[chunk][34816 rows][8]
//   else:        machine split -> Mch/Mcl[chunk][8192 rows][8]
// ---------------------------------------------------------------------------
__global__ __launch_bounds__(256) void prep_all(
    const float* __restrict__ Wq, const float* __restrict__ Wk,
    const float* __restrict__ Wv, const float* __restrict__ Wc,
    const float* __restrict__ jobs, const float* __restrict__ skip,
    const float* __restrict__ machine,
    unsigned short* __restrict__ Wh, unsigned short* __restrict__ Wl,
    unsigned short* __restrict__ Jh, unsigned short* __restrict__ Jl,
    unsigned short* __restrict__ Mh, unsigned short* __restrict__ Ml)
{
  __shared__ unsigned short sh[256], sl[256];
  const int bid = blockIdx.x;
  if (bid < 1024) {
    const int c = bid, k = threadIdx.x;
    const float* Ws = (c < 256) ? Wq : (c < 512) ? Wk : (c < 768) ? Wv : Wc;
    const float x = Ws[k * 256 + (c & 255)];
    const unsigned short h = f2bf(x);
    sh[k] = h; sl[k] = f2bf(x - bf2f(h));
    __syncthreads();
    if (k < 32)
      *(u16x8*)(Wh + ((size_t)k * 1024 + c) * 8) = *(const u16x8*)&sh[k * 8];
    else if (k < 64)
      *(u16x8*)(Wl + ((size_t)(k - 32) * 1024 + c) * 8) = *(const u16x8*)&sl[(k - 32) * 8];
  } else if (bid < 1568) {
    const int w = threadIdx.x >> 6, lane = threadIdx.x & 63;
    const int r = (bid - 1024) * 64 + lane;        // 0..34815
    const int bb = r / TPAD, tt = r - bb * TPAD;
    const bool padr = (tt >= 513);
    const float* src = (tt == 0) ? skip : (jobs + ((size_t)(bb * 512 + tt - 1) << 8));
    #pragma unroll
    for (int i = 0; i < 8; ++i) {
      const int cc = w * 8 + i;                    // chunk 0..31
      u16x8 h8 = {}, l8 = {};
      if (!padr) {
        const float4 a = *(const float4*)(src + cc * 8);
        const float4 b = *(const float4*)(src + cc * 8 + 4);
        const float v[8] = {a.x,a.y,a.z,a.w, b.x,b.y,b.z,b.w};
        #pragma unroll
        for (int j = 0; j < 8; ++j) {
          const unsigned short hh = f2bf(v[j]);
          h8[j] = hh;
          l8[j] = f2bf(v[j] - bf2f(hh));
        }
      }
      const size_t o = ((size_t)cc * NROWS + r) * 8;
      *(u16x8*)(Jh + o) = h8;
      *(u16x8*)(Jl + o) = l8;
    }
  } else {
    const int w = threadIdx.x >> 6, lane = threadIdx.x & 63;
    const int r = (bid - 1568) * 64 + lane;        // 0..8191
    const float* src = machine + ((size_t)r << 8);
    #pragma unroll
    for (int i = 0; i < 8; ++i) {
      const int cc = w * 8 + i;
      const float4 a = *(const float4*)(src + cc * 8);
      const float4 b = *(const float4*)(src + cc * 8 + 4);
      const float v[8] = {a.x,a.y,a.z,a.w, b.x,b.y,b.z,b.w};
      u16x8 h8, l8;
      #pragma unroll
      for (int j = 0; j < 8; ++j) {
        const unsigned short hh = f2bf(v[j]);
        h8[j] = hh;
        l8[j] = f2bf(v[j] - bf2f(hh));
      }
      const size_t o = ((size_t)cc * 8192 + r) * 8;
      *(u16x8*)(Mh + o) = h8;
      *(u16x8*)(Ml + o) = l8;
    }
  }
}

// ---------------------------------------------------------------------------
// kvq_mfma: ONE launch = KV projection (4352 blocks, R10 structure) + Q
// projection (512 blocks, proj structure, tail-overlapped). Identical 64x64
// skeleton: 4 waves = 2x2 (32x32), acc[2][2], uniform staging (4 contiguous
// 1KB global_load_lds per wave), vmcnt(4) depth-2 counted pipeline, 32KB LDS.
//   bid < 4352: C = vjobs_padded @ [Wk|Wv]; bx<4 -> K planes [34816][256];
//               bx>=4 -> V transposed planes [b][256][544] (u16x4 quads).
//   bid >= 4352: Q = machine @ Wq * 0.25 -> split planes (chunk-major).
// ---------------------------------------------------------------------------
__global__ __launch_bounds__(256) void kvq_mfma(
    const unsigned short* __restrict__ Jh, const unsigned short* __restrict__ Jl,
    const unsigned short* __restrict__ Wh, const unsigned short* __restrict__ Wl,
    const unsigned short* __restrict__ Mch, const unsigned short* __restrict__ Mcl,
    unsigned short* __restrict__ Kh, unsigned short* __restrict__ Kl,
    unsigned short* __restrict__ Vth, unsigned short* __restrict__ Vtl,
    unsigned short* __restrict__ Qh, unsigned short* __restrict__ Ql)
{
  __shared__ __align__(128) char smem[32768];  // 2 x {Ah 4K|Al 4K|Bh 4K|Bl 4K}
  const int tid = threadIdx.x;
  const int bid = blockIdx.x;
  const int w = __builtin_amdgcn_readfirstlane(tid >> 6);
  const int lane = tid & 63;
  const int wr = (w >> 1) << 5, wc = (w & 1) << 5;
  const int fm = lane & 15, fq = lane >> 4;
  const bool isq = (bid >= 4352);

  int bx, by;
  const unsigned short* sp;
  size_t rstride, base;
  if (!isq) {
    const int xcd = bid & 7, idx = bid >> 3;             // bijective (4352%8==0)
    bx = idx & 7;                                        // 0..3 K-col | 4..7 V-col
    by = xcd * 68 + (idx >> 3);                          // J row-tile 0..543
    sp = (w == 0) ? Jh : (w == 1) ? Jl : (w == 2) ? Wh : Wl;
    rstride = (w < 2) ? (size_t)NROWS : (size_t)1024;
    base    = (w < 2) ? (size_t)(by * 64) : (size_t)(256 + bx * 64);
  } else {
    const int lin = bid - 4352;                          // 0..511
    const int virt = (lin & 7) * 64 + (lin >> 3);        // bijective (512%8==0)
    bx = virt & 3; by = virt >> 2;
    sp = (w == 0) ? Mch : (w == 1) ? Mcl : (w == 2) ? Wh : Wl;
    rstride = (w < 2) ? (size_t)8192 : (size_t)1024;
    base    = (w < 2) ? (size_t)(by * 64) : (size_t)(bx * 64);   // Wq cols 0..255
  }
  const char* srcb = (const char*)sp + (base + lane) * 16;

  auto STAGE = [&](int ks, int bsel) {
    char* dst = smem + bsel * 16384 + w * 4096;
    #pragma unroll
    for (int j = 0; j < 4; ++j)
      GLD16(srcb + ((size_t)(ks * 4 + j)) * rstride * 16, dst + j * 1024);
  };

  f32x4 acc[2][2] = {};

  STAGE(0, 0);
  STAGE(1, 1);

  #pragma unroll
  for (int ks = 0; ks < 8; ++ks) {
    if (ks < 7) asm volatile("s_waitcnt vmcnt(4)" ::: "memory");
    else        asm volatile("s_waitcnt vmcnt(0)" ::: "memory");
    __builtin_amdgcn_s_barrier();
    __builtin_amdgcn_sched_barrier(0);

    char* cur = smem + (ks & 1) * 16384;
    bf16x8 afh[2], afl[2], bfh[2], bfl[2];
    #pragma unroll
    for (int i = 0; i < 2; ++i) {
      const int ro = fq * 1024 + (wr + i * 16 + fm) * 16;
      const int co = fq * 1024 + (wc + i * 16 + fm) * 16;
      afh[i] = *(const bf16x8*)(cur + ro);
      afl[i] = *(const bf16x8*)(cur + 4096 + ro);
      bfh[i] = *(const bf16x8*)(cur + 8192 + co);
      bfl[i] = *(const bf16x8*)(cur + 12288 + co);
    }
    #pragma unroll
    for (int mi = 0; mi < 2; ++mi)
      #pragma unroll
      for (int ni = 0; ni < 2; ++ni) {
        acc[mi][ni] = __builtin_amdgcn_mfma_f32_16x16x32_bf16(afh[mi], bfl[ni], acc[mi][ni], 0, 0, 0);
        acc[mi][ni] = __builtin_amdgcn_mfma_f32_16x16x32_bf16(afl[mi], bfh[ni], acc[mi][ni], 0, 0, 0);
        acc[mi][ni] = __builtin_amdgcn_mfma_f32_16x16x32_bf16(afh[mi], bfh[ni], acc[mi][ni], 0, 0, 0);
      }

    __builtin_amdgcn_s_barrier();
    if (ks + 2 < 8) STAGE(ks + 2, ks & 1);
  }

  // ---- epilogues ----
  if (isq) {
    // Q planes: x = acc * 0.25 (fold 1/sqrt(QKV)); chunk-major split
    const int colb = bx * 64 + wc;
    #pragma unroll
    for (int mi = 0; mi < 2; ++mi) {
      #pragma unroll
      for (int r = 0; r < 4; ++r) {
        const int row = by * 64 + wr + mi * 16 + fq * 4 + r;
        #pragma unroll
        for (int ni = 0; ni < 2; ++ni) {
          const int oc = colb + ni * 16 + fm;
          const float x = acc[mi][ni][r] * 0.25f;
          const unsigned short hh = f2bf(x);
          const size_t o = ((size_t)(oc >> 3) * 8192 + row) * 8 + (oc & 7);
          Qh[o] = hh;
          Ql[o] = f2bf(x - bf2f(hh));
        }
      }
    }
  } else if (bx < 4) {
    // K planes, row-major [34816][256]
    const int cb = bx * 64 + wc;
    #pragma unroll
    for (int mi = 0; mi < 2; ++mi) {
      #pragma unroll
      for (int r = 0; r < 4; ++r) {
        const int row = by * 64 + wr + mi * 16 + fq * 4 + r;
        const size_t rb = (size_t)row << 8;
        #pragma unroll
        for (int ni = 0; ni < 2; ++ni) {
          const int cc = cb + ni * 16 + fm;
          const float x = acc[mi][ni][r];
          const unsigned short hh = f2bf(x);
          Kh[rb + cc] = hh;
          Kl[rb + cc] = f2bf(x - bf2f(hh));
        }
      }
    }
  } else {
    // V transposed planes [b][256][544]; 4 consecutive t per frag reg quad
    const int cb = (bx - 4) * 64 + wc;
    #pragma unroll
    for (int mi = 0; mi < 2; ++mi) {
      const int row0 = by * 64 + wr + mi * 16 + fq * 4;   // 4-aligned
      const int bb = row0 / TPAD;
      const int tt0 = row0 - bb * TPAD;
      #pragma unroll
      for (int ni = 0; ni < 2; ++ni) {
        const int cc = cb + ni * 16 + fm;
        const size_t vb = ((size_t)(bb * 256 + cc)) * TPAD + tt0;
        u16x4 vh, vl;
        #pragma unroll
        for (int r = 0; r < 4; ++r) {
          const float x = acc[mi][ni][r];
          const unsigned short hh = f2bf(x);
          vh[r] = hh;
          vl[r] = f2bf(x - bf2f(hh));
        }
        *(u16x4*)(Vth + vb) = vh;
        *(u16x4*)(Vtl + vb) = vl;
      }
    }
  }
}

// ---------------------------------------------------------------------------
// proj_mfma (proj2 only): MH = OC @ Wc + bc -> split planes [chunk][8192][8].
// Tile 64x64, grid 512; 32KB dbuf; uniform 4-load staging; vmcnt(4).
// ---------------------------------------------------------------------------
__global__ __launch_bounds__(256) void proj_mfma(
    const unsigned short* __restrict__ Ah_, const unsigned short* __restrict__ Al_,
    const unsigned short* __restrict__ Wh_, const unsigned short* __restrict__ Wl_,
    const int cbase, const float* __restrict__ bias,
    unsigned short* __restrict__ Ch, unsigned short* __restrict__ Cl)
{
  __shared__ __align__(128) char smem[32768];  // 2 x {Ah 4K|Al 4K|Bh 4K|Bl 4K}
  const int tid = threadIdx.x;
  const int lin = blockIdx.x;                            // 0..511
  const int virt = (lin & 7) * 64 + (lin >> 3);          // bijective (512%8==0)
  const int bx = virt & 3, by = virt >> 2;               // col-tile(64), row-tile(64)
  const int w = __builtin_amdgcn_readfirstlane(tid >> 6);
  const int lane = tid & 63;
  const int wr = (w >> 1) << 5, wc = (w & 1) << 5;
  const int fm = lane & 15, fq = lane >> 4;

  const unsigned short* sp = (w == 0) ? Ah_ : (w == 1) ? Al_ : (w == 2) ? Wh_ : Wl_;
  const size_t rstride = (w < 2) ? (size_t)8192 : (size_t)1024;
  const size_t base = (w < 2) ? (size_t)(by * 64) : (size_t)(cbase + bx * 64);
  const char* srcb = (const char*)sp + (base + lane) * 16;

  auto STAGE = [&](int ks, int bsel) {
    char* dst = smem + bsel * 16384 + w * 4096;
    #pragma unroll
    for (int j = 0; j < 4; ++j)
      GLD16(srcb + ((size_t)(ks * 4 + j)) * rstride * 16, dst + j * 1024);
  };

  f32x4 acc[2][2] = {};

  STAGE(0, 0);
  STAGE(1, 1);

  #pragma unroll
  for (int ks = 0; ks < 8; ++ks) {
    if (ks < 7) asm volatile("s_waitcnt vmcnt(4)" ::: "memory");
    else        asm volatile("s_waitcnt vmcnt(0)" ::: "memory");
    __builtin_amdgcn_s_barrier();
    __builtin_amdgcn_sched_barrier(0);

    char* cur = smem + (ks & 1) * 16384;
    bf16x8 afh[2], afl[2], bfh[2], bfl[2];
    #pragma unroll
    for (int i = 0; i < 2; ++i) {
      const int ro = fq * 1024 + (wr + i * 16 + fm) * 16;
      const int co = fq * 1024 + (wc + i * 16 + fm) * 16;
      afh[i] = *(const bf16x8*)(cur + ro);
      afl[i] = *(const bf16x8*)(cur + 4096 + ro);
      bfh[i] = *(const bf16x8*)(cur + 8192 + co);
      bfl[i] = *(const bf16x8*)(cur + 12288 + co);
    }
    #pragma unroll
    for (int mi = 0; mi < 2; ++mi)
      #pragma unroll
      for (int ni = 0; ni < 2; ++ni) {
        acc[mi][ni] = __builtin_amdgcn_mfma_f32_16x16x32_bf16(afh[mi], bfl[ni], acc[mi][ni], 0, 0, 0);
        acc[mi][ni] = __builtin_amdgcn_mfma_f32_16x16x32_bf16(afl[mi], bfh[ni], acc[mi][ni], 0, 0, 0);
        acc[mi][ni] = __builtin_amdgcn_mfma_f32_16x16x32_bf16(afh[mi], bfh[ni], acc[mi][ni], 0, 0, 0);
      }

    __builtin_amdgcn_s_barrier();
    if (ks + 2 < 8) STAGE(ks + 2, ks & 1);
  }

  // epilogue: x = acc + bias; split RNE hi/lo into chunk-major planes
  const int colb = bx * 64 + wc;
  #pragma unroll
  for (int mi = 0; mi < 2; ++mi) {
    #pragma unroll
    for (int r = 0; r < 4; ++r) {
      const int row = by * 64 + wr + mi * 16 + fq * 4 + r;
      #pragma unroll
      for (int ni = 0; ni < 2; ++ni) {
        const int oc = colb + ni * 16 + fm;
        const float x = acc[mi][ni][r] + bias[oc];
        const unsigned short hh = f2bf(x);
        const size_t o = ((size_t)(oc >> 3) * 8192 + row) * 8 + (oc & 7);
        Ch[o] = hh;
        Cl[o] = f2bf(x - bf2f(hh));
      }
    }
  }
}

// ---------------------------------------------------------------------------
// MFMA attention v9: one block per (h, b), 4 waves (m-half x t-half).
// Q read as pre-split planes (scale folded); K/V as pre-split planes (hi for
// lane groups 0,1; lo for 2,3); V transposed (contiguous t). Output written
// as split OC planes [chunk][8192][8] feeding proj_mfma directly.
// Pads t=513..543 are zero -> exp=1 exactly: subtract 31 from l.
// ---------------------------------------------------------------------------
__global__ __launch_bounds__(256, 4) void attn_mfma(
    const unsigned short* __restrict__ Qh, const unsigned short* __restrict__ Ql,
    const unsigned short* __restrict__ Kh, const unsigned short* __restrict__ Kl,
    const unsigned short* __restrict__ Vth, const unsigned short* __restrict__ Vtl,
    unsigned short* __restrict__ Och, unsigned short* __restrict__ Ocl)
{
  const int h = blockIdx.x, b = blockIdx.y;
  const int tid = threadIdx.x;
  const int lane = tid & 63;
  const int w = __builtin_amdgcn_readfirstlane(tid >> 6);
  const int g = lane >> 4, fm = lane & 15;
  const int mh = (w & 2) << 5;              // 0 or 64
  const int th = w & 1;                     // t-half
  const int send = th ? 17 : 9;             // steps [0,9) | [9,17)
  int s = th ? 9 : 0;

  __shared__ float red[2 * 64 * 21];        // 10.5 KB, stride-21 (conflict-free)

  const int col = h * 16;

  // ---- Q B-frags from pre-split planes: Bq1 = hi, Bq2 = lo (g<2) | 0 ----
  bf16x8 Bq1[4], Bq2[4];
  const bf16x8 zf = {};
  #pragma unroll
  for (int mt = 0; mt < 4; ++mt) {
    const size_t qo = ((size_t)(h * 2 + (g & 1)) * 8192
                      + (b * 128 + mh + mt * 16 + fm)) * 8;
    Bq1[mt] = *(const bf16x8*)(Qh + qo);
    Bq2[mt] = (g < 2) ? *(const bf16x8*)(Ql + qo) : zf;
  }

  f32x4 oT[4] = {};
  float lsum[4] = {0.f, 0.f, 0.f, 0.f};

  const int rA = ((fm & 12) << 1) + (fm & 3);   // permuted K row within step
  const int dbase = (g & 1) << 3;
  const unsigned short* kpl = ((g < 2) ? Kh : Kl)
      + ((((size_t)b * TPAD) + rA) << 8) + col + dbase;
  const unsigned short* vhp = Vth + ((size_t)(b * 256 + col + fm)) * TPAD + (g << 3);
  const unsigned short* vlp = Vtl + ((size_t)(b * 256 + col + fm)) * TPAD + (g << 3);

  for (; s < send; ++s) {
    const int t0 = s << 5;
    const bf16x8 KA = *(const bf16x8*)(kpl + ((size_t)t0 << 8));
    const bf16x8 KB = *(const bf16x8*)(kpl + ((size_t)(t0 + 4) << 8));
    const bf16x8 Vh = *(const bf16x8*)(vhp + t0);
    const bf16x8 Vl = *(const bf16x8*)(vlp + t0);

    #pragma unroll
    for (int mt = 0; mt < 4; ++mt) {
      f32x4 sA = {}, sB = {};
      sA = __builtin_amdgcn_mfma_f32_16x16x32_bf16(KA, Bq1[mt], sA, 0, 0, 0);
      sA = __builtin_amdgcn_mfma_f32_16x16x32_bf16(KA, Bq2[mt], sA, 0, 0, 0);
      sB = __builtin_amdgcn_mfma_f32_16x16x32_bf16(KB, Bq1[mt], sB, 0, 0, 0);
      sB = __builtin_amdgcn_mfma_f32_16x16x32_bf16(KB, Bq2[mt], sB, 0, 0, 0);
      float p[8];
      p[0] = __expf(sA[0]); p[1] = __expf(sA[1]); p[2] = __expf(sA[2]); p[3] = __expf(sA[3]);
      p[4] = __expf(sB[0]); p[5] = __expf(sB[1]); p[6] = __expf(sB[2]); p[7] = __expf(sB[3]);
      lsum[mt] += ((p[0] + p[1]) + (p[2] + p[3])) + ((p[4] + p[5]) + (p[6] + p[7]));
      bf16x8 Ph, Pl;
      #pragma unroll
      for (int jp = 0; jp < 4; ++jp) {
        const unsigned u0 = __float_as_uint(p[2*jp]);
        const unsigned u1 = __float_as_uint(p[2*jp+1]);
        ((unsigned*)&Ph)[jp] = __builtin_amdgcn_perm(u1, u0, 0x07060302u);
        const float r0 = p[2*jp]   - __uint_as_float(u0 & 0xffff0000u);
        const float r1 = p[2*jp+1] - __uint_as_float(u1 & 0xffff0000u);
        unsigned t0_ = __float_as_uint(r0); t0_ += 0x7fffu + ((t0_ >> 16) & 1u);
        unsigned t1_ = __float_as_uint(r1); t1_ += 0x7fffu + ((t1_ >> 16) & 1u);
        ((unsigned*)&Pl)[jp] = __builtin_amdgcn_perm(t1_, t0_, 0x07060302u);
      }
      oT[mt] = __builtin_amdgcn_mfma_f32_16x16x32_bf16(Vh, Ph, oT[mt], 0, 0, 0);
      oT[mt] = __builtin_amdgcn_mfma_f32_16x16x32_bf16(Vh, Pl, oT[mt], 0, 0, 0);
      oT[mt] = __builtin_amdgcn_mfma_f32_16x16x32_bf16(Vl, Ph, oT[mt], 0, 0, 0);
    }
  }

  // ---- pair reduce (t-half 1 -> t-half 0), then normalize + write planes ----
  float* slot = red + ((w >> 1) * 1344);
  const int base = lane * 21;
  if (th) {
    #pragma unroll
    for (int mt = 0; mt < 4; ++mt) {
      slot[base + 4 * mt + 0] = oT[mt][0];
      slot[base + 4 * mt + 1] = oT[mt][1];
      slot[base + 4 * mt + 2] = oT[mt][2];
      slot[base + 4 * mt + 3] = oT[mt][3];
      slot[base + 16 + mt]    = lsum[mt];
    }
  }
  __syncthreads();
  if (!th) {
    #pragma unroll
    for (int mt = 0; mt < 4; ++mt) {
      oT[mt][0] += slot[base + 4 * mt + 0];
      oT[mt][1] += slot[base + 4 * mt + 1];
      oT[mt][2] += slot[base + 4 * mt + 2];
      oT[mt][3] += slot[base + 4 * mt + 3];
      float v = lsum[mt] + slot[base + 16 + mt];
      v += __shfl_xor(v, 16);
      v += __shfl_xor(v, 32);
      const float inv = 1.f / (v - 31.f);     // remove 31 pad rows (exp(0)=1)
      // oT reg r = out[m][d = 4g + r] -> chunk h*2+(g>>1), slot (g&1)*4 + r
      const int row = b * 128 + mh + mt * 16 + fm;
      const size_t oo = ((size_t)(h * 2 + (g >> 1)) * 8192 + row) * 8 + ((g & 1) << 2);
      u16x4 oh, ol;
      #pragma unroll
      for (int r = 0; r < 4; ++r) {
        const float x = oT[mt][r] * inv;
        const unsigned short hh = f2bf(x);
        oh[r] = hh;
        ol[r] = f2bf(x - bf2f(hh));
      }
      *(u16x4*)(Och + oo) = oh;
      *(u16x4*)(Ocl + oo) = ol;
    }
  }
}

// ---------------------------------------------------------------------------
// Logits v3: tile 128m x 64t, grid 9 x 64 = 576 blocks; 48KB dbuf ->
// 3 blocks/CU. Waves 0/1 stage Mh/Ml (8 loads), 2/3 Jh/Jl (4 loads); counted
// vmcnt. Cheap tanh: e = exp(mask - 20/(exp(acc/8)+1)). tx=8 tail guarded +
// J-row clamped. Deterministic partials[b*9+tx]; sm_inv folded into sm_norm.
// ---------------------------------------------------------------------------
__global__ __launch_bounds__(256) void logits_mfma(
    const unsigned short* __restrict__ Mh, const unsigned short* __restrict__ Ml,
    const unsigned short* __restrict__ Jh, const unsigned short* __restrict__ Jl,
    const float* __restrict__ mask,
    float* __restrict__ out, float* __restrict__ partials)
{
  __shared__ __align__(128) char smem[49152];  // 2 x {Ah 8K|Al 8K|Bh 4K|Bl 4K}
  __shared__ float red[4];
  const int tid = threadIdx.x;
  const int lin = blockIdx.x + blockIdx.y * 9;           // 0..575
  const int virt = (lin & 7) * 72 + (lin >> 3);          // bijective (576%8==0)
  const int tx = virt % 9;                               // t-tile 0..8
  const int b  = virt / 9;
  const int w = __builtin_amdgcn_readfirstlane(tid >> 6);
  const int lane = tid & 63;
  const int wr = (w >> 1) << 6;              // m-half: 0 | 64
  const int wtc = (w & 1) << 5;              // t-half: 0 | 32
  const int fm = lane & 15, fq = lane >> 4;

  const unsigned short* sp = (w == 0) ? Mh : (w == 1) ? Ml : (w == 2) ? Jh : Jl;
  int jrow = b * TPAD + tx * 64 + lane;      // clamp tx=8 tail (guarded cols only)
  if (jrow > NROWS - 1) jrow = NROWS - 1;
  const char* srcb = (w < 2)
      ? (const char*)sp + ((size_t)(b * 128) + lane) * 16
      : (const char*)sp + (size_t)jrow * 16;

  auto STAGE = [&](int ks, int bsel) {
    char* buf = smem + bsel * 24576;
    if (w < 2) {                             // M planes: 128 rows, 8 loads
      char* dst = buf + (w ? 8192 : 0);
      #pragma unroll
      for (int j = 0; j < 8; ++j) {
        const int fq_ = j >> 1, half = j & 1;
        GLD16(srcb + (((size_t)(ks * 4 + fq_)) * 8192 + half * 64) * 16,
              dst + fq_ * 2048 + half * 1024);
      }
    } else {                                 // J planes: 64 rows, 4 loads
      char* dst = buf + 16384 + ((w == 3) ? 4096 : 0);
      #pragma unroll
      for (int j = 0; j < 4; ++j)
        GLD16(srcb + ((size_t)(ks * 4 + j)) * ((size_t)NROWS * 16),
              dst + j * 1024);
    }
  };

  f32x4 acc[4][2] = {};

  STAGE(0, 0);
  STAGE(1, 1);

  #pragma unroll
  for (int ks = 0; ks < 8; ++ks) {
    if (ks < 7) {
      if (w < 2) asm volatile("s_waitcnt vmcnt(8)" ::: "memory");
      else       asm volatile("s_waitcnt vmcnt(4)" ::: "memory");
    } else {
      asm volatile("s_waitcnt vmcnt(0)" ::: "memory");
    }
    __builtin_amdgcn_s_barrier();
    __builtin_amdgcn_sched_barrier(0);

    char* cur = smem + (ks & 1) * 24576;
    bf16x8 afh[4], afl[4], bfh[2], bfl[2];
    #pragma unroll
    for (int i = 0; i < 4; ++i) {
      const int ro = fq * 2048 + (wr + i * 16 + fm) * 16;
      afh[i] = *(const bf16x8*)(cur + ro);
      afl[i] = *(const bf16x8*)(cur + 8192 + ro);
    }
    #pragma unroll
    for (int n = 0; n < 2; ++n) {
      const int co = fq * 1024 + (wtc + n * 16 + fm) * 16;
      bfh[n] = *(const bf16x8*)(cur + 16384 + co);
      bfl[n] = *(const bf16x8*)(cur + 20480 + co);
    }
    #pragma unroll
    for (int mi = 0; mi < 4; ++mi)
      #pragma unroll
      for (int ni = 0; ni < 2; ++ni) {
        acc[mi][ni] = __builtin_amdgcn_mfma_f32_16x16x32_bf16(afh[mi], bfl[ni], acc[mi][ni], 0, 0, 0);
        acc[mi][ni] = __builtin_amdgcn_mfma_f32_16x16x32_bf16(afl[mi], bfh[ni], acc[mi][ni], 0, 0, 0);
        acc[mi][ni] = __builtin_amdgcn_mfma_f32_16x16x32_bf16(afh[mi], bfh[ni], acc[mi][ni], 0, 0, 0);
      }

    __builtin_amdgcn_s_barrier();
    if (ks + 2 < 8) STAGE(ks + 2, ks & 1);
  }

  // epilogue: e = exp(mask - 20/(exp(acc/8)+1)); write; deterministic partial
  float lsum = 0.f;
  #pragma unroll
  for (int mi = 0; mi < 4; ++mi) {
    #pragma unroll
    for (int r = 0; r < 4; ++r) {
      const int m = wr + mi * 16 + fq * 4 + r;
      #pragma unroll
      for (int ni = 0; ni < 2; ++ni) {
        const int t = tx * 64 + wtc + ni * 16 + fm;
        if (t < 513) {
          const float e2 = __expf(acc[mi][ni][r] * 0.125f);
          const float e  = __expf(mask[((size_t)(b * 128 + m)) * 513 + t]
                                  - 20.f / (e2 + 1.f));
          out[(size_t)b * 65664 + (size_t)m * 513 + t] = e;
          lsum += e;
        }
      }
    }
  }
  #pragma unroll
  for (int off = 32; off; off >>= 1) lsum += __shfl_xor(lsum, off);
  if (lane == 0) red[w] = lsum;
  __syncthreads();
  if (tid == 0)
    partials[b * 9 + tx] = (red[0] + red[1]) + (red[2] + red[3]);
}

// Normalize: inv computed inline from 9 deterministic partials (L1-hot).
__global__ __launch_bounds__(256) void sm_norm(float* __restrict__ out,
                                               const float* __restrict__ partials)
{
  const int i4 = blockIdx.x * 256 + threadIdx.x;
  if (i4 < 1050624) {
    const int b = i4 / 16416;
    float s = 0.f;
    #pragma unroll
    for (int i = 0; i < 9; ++i) s += partials[b * 9 + i];
    const float inv = 1.f / s;
    float4 v = ((float4*)out)[i4];
    v.x *= inv; v.y *= inv; v.z *= inv; v.w *= inv;
    ((float4*)out)[i4] = v;
  }
}

// ---------------------------------------------------------------------------
extern "C" void kernel_launch(void* const* d_in, const int* in_sizes, int n_in,
                              void* d_out, int out_size, void* d_ws, size_t ws_size,
                              hipStream_t stream)
{
  const float* machine = (const float*)d_in[0];
  const float* jobs    = (const float*)d_in[1];
  const float* mask    = (const float*)d_in[2];
  const float* Wq      = (const float*)d_in[3];
  const float* Wk      = (const float*)d_in[4];
  const float* Wv      = (const float*)d_in[5];
  const float* Wc      = (const float*)d_in[6];
  const float* bc      = (const float*)d_in[7];
  const float* skip    = (const float*)d_in[8];

  // Workspace (floats). Peak ~29,098,560 f ~ 116.4 MB.
  //   [0,        8912896)  Jh|Jl chunk-major jobs planes (LIVE until logits)
  //   [8912896, 17825792)  Kh|Kl planes [34816][256] (dead after attn)
  //        overlays after attn: Mh|Ml MH planes (proj2 output, 2.1M f)
  //   [17825792,26738688)  Vth|Vtl transposed planes [64][256][544]
  //   [26738688,27000832)  Wah|Wal all-W planes [32][1024][8] hi/lo
  //   [27000832,29097984)  Mch|Mcl machine planes [32][8192][8] hi/lo
  //   [29097984,29098560)  partials (576 f)
  // d_out (4,202,496 f) scratch pre-logits: Qh|Ql [0,2.1M f), Och|Ocl [2.1M,4.2M f).
  float* ws       = (float*)d_ws;
  unsigned short* JhP = (unsigned short*)ws;
  unsigned short* JlP = JhP + 8912896;
  unsigned short* KhP = (unsigned short*)(ws + 8912896);
  unsigned short* KlP = KhP + 8912896;
  unsigned short* VthP = (unsigned short*)(ws + 17825792);
  unsigned short* VtlP = VthP + 8912896;
  unsigned short* WahP = (unsigned short*)(ws + 26738688);
  unsigned short* WalP = WahP + 262144;
  unsigned short* MchP = (unsigned short*)(ws + 27000832);
  unsigned short* MclP = MchP + 2097152;
  unsigned short* MhP  = (unsigned short*)(ws + 8912896);   // overlays Kh (dead after attn)
  unsigned short* MlP  = MhP + 2097152;
  float* partials = ws + 29097984;
  float* out      = (float*)d_out;
  unsigned short* QhP  = (unsigned short*)out;              // d_out scratch
  unsigned short* QlP  = QhP + 2097152;
  unsigned short* OchP = QlP + 2097152;
  unsigned short* OclP = OchP + 2097152;

  // ONE prep launch: W planes + jobs planes + machine planes
  prep_all<<<1696, 256, 0, stream>>>(
      Wq, Wk, Wv, Wc, jobs, skip, machine,
      WahP, WalP, JhP, JlP, MchP, MclP);
  // ONE launch: K|V projection (4352 blocks) + Q projection (512, tail-overlap)
  kvq_mfma<<<4864, 256, 0, stream>>>(
      JhP, JlP, WahP, WalP, MchP, MclP,
      KhP, KlP, VthP, VtlP, QhP, QlP);
  // MFMA attention -> OC split planes (d_out scratch)
  attn_mfma<<<dim3(16, 64), 256, 0, stream>>>(
      QhP, QlP, KhP, KlP, VthP, VtlP, OchP, OclP);
  // MH = OC @ Wc + bc -> split planes (overlay K region)
  proj_mfma<<<512, 256, 0, stream>>>(
      OchP, OclP, WahP, WalP, 768, bc, MhP, MlP);
  // logits v3 + fused exp epilogue + partials
  logits_mfma<<<dim3(9, 64), 256, 0, stream>>>(
      MhP, MlP, JhP, JlP, mask, out, partials);
  sm_norm<<<4104, 256, 0, stream>>>(out, partials);
}